// Round 2
// baseline (6293.658 us; speedup 1.0000x reference)
//
#include <hip/hip_runtime.h>
#include <hip/hip_bf16.h>

#define NN 16384          // gate nodes
#define BBG 64            // graphs
#define EE 49152          // directed edges (no self loops)
#define ET (EE + NN)      // edges + self loops = 65536
#define DD 512            // node feature dim (2F)
#define NG (NN / BBG)     // 256 nodes per graph
#define MAXDEG 96

// ---------------------------------------------------------------------------
// fp32 GEMM: C[M,N] = act(A[M,K] @ W[K,N] + bias), fp32 accumulate.
// 64x64 block tile, BK=16, 256 threads, 4x4 microtile per thread.
// Requires M%64==0, N%64==0, K%16==0 (true for every GEMM in this net).
// ---------------------------------------------------------------------------
__global__ __launch_bounds__(256) void gemm_f32(
    const float* __restrict__ A, const float* __restrict__ W,
    const float* __restrict__ bias, float* __restrict__ C,
    int M, int N, int K, float slope, int has_act)
{
    const int BK = 16;
    __shared__ float As[BK][64 + 1];
    __shared__ float Ws[BK][64 + 1];
    int tid = threadIdx.x;
    int bm = blockIdx.y * 64;
    int bn = blockIdx.x * 64;
    int tr = tid >> 4;      // 0..15  (row group)
    int tc = tid & 15;      // 0..15  (col group)
    float acc[4][4] = {};

    for (int k0 = 0; k0 < K; k0 += BK) {
        // A tile: 64 rows x 16 k-cols
        {
            int col = tid & 15;
            int row = tid >> 4;
#pragma unroll
            for (int p = 0; p < 4; p++) {
                int r = row + p * 16;
                As[col][r] = A[(size_t)(bm + r) * K + k0 + col];
            }
        }
        // W tile: 16 k-rows x 64 cols
        {
            int wc = tid & 63;
            int wr = tid >> 6;
#pragma unroll
            for (int p = 0; p < 4; p++) {
                int r = wr + p * 4;
                Ws[r][wc] = W[(size_t)(k0 + r) * N + bn + wc];
            }
        }
        __syncthreads();
#pragma unroll
        for (int kk = 0; kk < BK; kk++) {
            float a[4], w[4];
#pragma unroll
            for (int i = 0; i < 4; i++) a[i] = As[kk][tr * 4 + i];
#pragma unroll
            for (int j = 0; j < 4; j++) w[j] = Ws[kk][tc * 4 + j];
#pragma unroll
            for (int i = 0; i < 4; i++)
#pragma unroll
                for (int j = 0; j < 4; j++)
                    acc[i][j] += a[i] * w[j];
        }
        __syncthreads();
    }

#pragma unroll
    for (int i = 0; i < 4; i++) {
        int r = bm + tr * 4 + i;
#pragma unroll
        for (int j = 0; j < 4; j++) {
            int cn = bn + tc * 4 + j;
            float v = acc[i][j];
            if (bias) v += bias[cn];
            if (has_act) v = (v >= 0.f) ? v : v * slope;
            C[(size_t)r * N + cn] = v;
        }
    }
}

// ---------------------------------------------------------------------------
// CSR build over dst (includes self loops: edge ids [EE, ET) are node e-EE)
// ---------------------------------------------------------------------------
__device__ __forceinline__ int clampi(int v, int lo, int hi)
{
    return v < lo ? lo : (v > hi ? hi : v);
}

__global__ void count_deg(const int* __restrict__ ei, int* __restrict__ deg)
{
    int e = blockIdx.x * 256 + threadIdx.x;
    if (e >= ET) return;
    int d = (e < EE) ? ei[EE + e] : (e - EE);
    d = clampi(d, 0, NN - 1);
    atomicAdd(&deg[d], 1);
}

__global__ __launch_bounds__(256) void scan_deg(const int* __restrict__ deg,
                                                int* __restrict__ rs)
{
    __shared__ int part[256];
    __shared__ int psum[257];
    int tid = threadIdx.x;
    const int per = NN / 256;   // 64
    int base = tid * per;
    int s = 0;
    for (int i = 0; i < per; i++) s += deg[base + i];
    part[tid] = s;
    __syncthreads();
    if (tid == 0) {
        int acc = 0;
        for (int i = 0; i < 256; i++) { psum[i] = acc; acc += part[i]; }
        psum[256] = acc;
    }
    __syncthreads();
    int acc = psum[tid];
    for (int i = 0; i < per; i++) { rs[base + i] = acc; acc += deg[base + i]; }
    if (tid == 0) rs[NN] = psum[256];
}

__global__ void fill_csr(const int* __restrict__ ei, const int* __restrict__ rs,
                         int* __restrict__ cur, int* __restrict__ csrc,
                         int* __restrict__ ceid)
{
    int e = blockIdx.x * 256 + threadIdx.x;
    if (e >= ET) return;
    int s, d;
    if (e < EE) { s = ei[e]; d = ei[EE + e]; } else { s = d = e - EE; }
    s = clampi(s, 0, NN - 1);
    d = clampi(d, 0, NN - 1);
    int pos = atomicAdd(&cur[d], 1);
    int slot = clampi(rs[d] + pos, 0, ET - 1);
    csrc[slot] = s;
    ceid[slot] = e;
}

// ---------------------------------------------------------------------------
// Edge logits: one wave per edge. logit[e,h] = sum_c att[h,c]*lrelu0.2(xl[s]+xr[d])
// ---------------------------------------------------------------------------
__global__ __launch_bounds__(256) void edge_logits(
    const float* __restrict__ xl, const float* __restrict__ xr,
    const float* __restrict__ att, const int* __restrict__ ei,
    float* __restrict__ logit, int H, int HC)
{
    int e = blockIdx.x * 4 + (threadIdx.x >> 6);
    if (e >= ET) return;
    int lane = threadIdx.x & 63;
    int s, d;
    if (e < EE) { s = ei[e]; d = ei[EE + e]; } else { s = d = e - EE; }
    s = clampi(s, 0, NN - 1);
    d = clampi(d, 0, NN - 1);
    for (int h = 0; h < H; h++) {
        const float* pl = xl + (size_t)s * HC + h * DD;
        const float* pr = xr + (size_t)d * HC + h * DD;
        const float* pa = att + h * DD;
        float acc = 0.f;
        for (int c = lane; c < DD; c += 64) {
            float v = pl[c] + pr[c];
            v = (v >= 0.f) ? v : 0.2f * v;
            acc += pa[c] * v;
        }
#pragma unroll
        for (int off = 32; off; off >>= 1) acc += __shfl_down(acc, off);
        if (lane == 0) logit[(size_t)e * H + h] = acc;
    }
}

// ---------------------------------------------------------------------------
// Per-node softmax over in-edges + weighted aggregation of xl[src].
// out[n,c] = lrelu0.01( sum_e alpha[e,h(c)]*xl[src_e,c] + b[c] ) (+ res[n,c])
// ---------------------------------------------------------------------------
__global__ __launch_bounds__(256) void gat_aggregate(
    const float* __restrict__ xl, const float* __restrict__ logit,
    const float* __restrict__ bias, const int* __restrict__ rs,
    const int* __restrict__ csrc, const int* __restrict__ ceid,
    const float* __restrict__ res, float* __restrict__ out, int H, int HC)
{
    int n = blockIdx.x;
    int tid = threadIdx.x;
    int start = rs[n];
    int deg = rs[n + 1] - start;
    deg = clampi(deg, 1, MAXDEG);   // structurally <= ~20 for this graph dist
    start = clampi(start, 0, ET - 1);
    __shared__ float s_alpha[2 * MAXDEG];
    __shared__ int s_src[MAXDEG];
    if (tid == 0) {
        for (int h = 0; h < H; h++) {
            float m = -1e30f;
            for (int i = 0; i < deg; i++) {
                int eid = clampi(ceid[start + i], 0, ET - 1);
                m = fmaxf(m, logit[(size_t)eid * H + h]);
            }
            float den = 0.f;
            for (int i = 0; i < deg; i++) {
                int eid = clampi(ceid[start + i], 0, ET - 1);
                float p = __expf(logit[(size_t)eid * H + h] - m);
                s_alpha[h * MAXDEG + i] = p;
                den += p;
            }
            float inv = 1.f / den;
            for (int i = 0; i < deg; i++) s_alpha[h * MAXDEG + i] *= inv;
        }
    }
    if (tid < deg) s_src[tid] = clampi(csrc[start + tid], 0, NN - 1);
    __syncthreads();
    for (int c = tid; c < HC; c += 256) {
        int h = c / DD;
        float acc = bias[c];
        for (int i = 0; i < deg; i++)
            acc += s_alpha[h * MAXDEG + i] * xl[(size_t)s_src[i] * HC + c];
        acc = (acc >= 0.f) ? acc : 0.01f * acc;
        if (res) acc += res[(size_t)n * HC + c];
        out[(size_t)n * HC + c] = acc;
    }
}

// ---------------------------------------------------------------------------
// Graph LayerNorm stats: mean/inv_std over (256 nodes x 512 ch) per graph
// ---------------------------------------------------------------------------
__global__ __launch_bounds__(256) void ln_stats(const float* __restrict__ h,
                                                float* __restrict__ mean,
                                                float* __restrict__ inv)
{
    int g = blockIdx.x;
    int tid = threadIdx.x;
    const int tot = NG * DD;    // 131072
    size_t base = (size_t)g * tot;
    float s = 0.f, s2 = 0.f;
    for (int i = tid; i < tot; i += 256) {
        float v = h[base + i];
        s += v; s2 += v * v;
    }
    __shared__ float ls[256], ls2[256];
    ls[tid] = s; ls2[tid] = s2;
    __syncthreads();
    for (int o = 128; o; o >>= 1) {
        if (tid < o) { ls[tid] += ls[tid + o]; ls2[tid] += ls2[tid + o]; }
        __syncthreads();
    }
    if (tid == 0) {
        float m = ls[0] / tot;
        float var = ls2[0] / tot - m * m;
        mean[g] = m;
        inv[g] = rsqrtf(fmaxf(var, 0.f) + 1e-5f);
    }
}

// ---------------------------------------------------------------------------
// Apply LN (channel affine) + channel-wise softmax aggregation over nodes.
// One thread per (graph, channel); loops the 256 nodes twice (L2-resident).
// ---------------------------------------------------------------------------
__global__ __launch_bounds__(256) void graph_aggr(
    const float* __restrict__ h, const float* __restrict__ mean,
    const float* __restrict__ inv, const float* __restrict__ lnw,
    const float* __restrict__ lnb, const float* __restrict__ t_,
    float* __restrict__ gout)
{
    int g = blockIdx.x;
    int c = blockIdx.y * 256 + threadIdx.x;   // 0..511
    float mu = mean[g], iv = inv[g];
    float w = lnw[c], bia = lnb[c];
    float t = t_[0];
    size_t base = (size_t)g * NG * DD + c;
    float mx = -1e30f;
    for (int i = 0; i < NG; i++) {
        float hn = (h[base + (size_t)i * DD] - mu) * iv * w + bia;
        mx = fmaxf(mx, hn * t);
    }
    float den = 0.f, acc = 0.f;
    for (int i = 0; i < NG; i++) {
        float hn = (h[base + (size_t)i * DD] - mu) * iv * w + bia;
        float p = __expf(hn * t - mx);
        den += p;
        acc += p * hn;
    }
    gout[(size_t)g * DD + c] = acc / den;
}

// ---------------------------------------------------------------------------
extern "C" void kernel_launch(void* const* d_in, const int* in_sizes, int n_in,
                              void* d_out, int out_size, void* d_ws, size_t ws_size,
                              hipStream_t stream)
{
    const float* x      = (const float*)d_in[0];
    const int*   ei     = (const int*)d_in[1];
    // d_in[2] = batch (structurally arange(N)//256, unused)
    const float* xt_w1  = (const float*)d_in[3];
    const float* xt_b1  = (const float*)d_in[4];
    const float* xt_w2  = (const float*)d_in[5];
    const float* xt_b2  = (const float*)d_in[6];
    const float* ln_w   = (const float*)d_in[27];
    const float* ln_b   = (const float*)d_in[28];
    const float* aggr_t = (const float*)d_in[29];
    const float* m_w1   = (const float*)d_in[30];
    const float* m_b1   = (const float*)d_in[31];
    const float* m_w2   = (const float*)d_in[32];
    const float* m_b2   = (const float*)d_in[33];
    const float* m_w3   = (const float*)d_in[34];
    const float* m_b3   = (const float*)d_in[35];
    float* out = (float*)d_out;

    // ---- workspace layout (256B aligned); small int/aux buffers FIRST so
    // that any hypothetical ws overflow hits float buffers (finite garbage),
    // never the index arrays ----
    char* p = (char*)d_ws;
    auto take = [&](size_t bytes) {
        char* r = p;
        p += (bytes + 255) & ~(size_t)255;
        return r;
    };
    int* i_deg    = (int*)take((size_t)(NN + 1) * 4);
    int* i_rs     = (int*)take((size_t)(NN + 1) * 4);
    int* i_cur    = (int*)take((size_t)NN * 4);
    int* i_src    = (int*)take((size_t)ET * 4);
    int* i_eid    = (int*)take((size_t)ET * 4);
    float* f_logit = (float*)take((size_t)ET * 2 * 4);
    float* f_lnm  = (float*)take(BBG * 4);
    float* f_lni  = (float*)take(BBG * 4);
    float* b_g    = (float*)take((size_t)BBG * DD * 4);
    float* b_m1   = (float*)take((size_t)BBG * 384 * 4);
    float* b_m2   = (float*)take((size_t)BBG * 256 * 4);
    float* b_res  = (float*)take((size_t)NN * DD * 4);      // cx / residual
    float* b_h    = (float*)take((size_t)NN * 1024 * 4);    // current node feats
    float* b_xl   = (float*)take((size_t)NN * 1024 * 4);    // source proj (alias t1)
    float* b_xr   = (float*)take((size_t)NN * 1024 * 4);    // target proj
    float* b_t1 = b_xl;   // [32768,256] x_trans intermediate, dead before GAT

    dim3 blk(256);

    // ---- CSR build (graph fixed per call, rebuilt every launch) ----
    hipMemsetAsync(i_deg, 0, (size_t)(NN + 1) * 4, stream);
    hipMemsetAsync(i_cur, 0, (size_t)NN * 4, stream);
    count_deg<<<ET / 256, blk, 0, stream>>>(ei, i_deg);
    scan_deg<<<1, blk, 0, stream>>>(i_deg, i_rs);
    fill_csr<<<ET / 256, blk, 0, stream>>>(ei, i_rs, i_cur, i_src, i_eid);

    // ---- x_trans: [32768,32] -> lr -> [32768,256] -> [32768,256] ----
    gemm_f32<<<dim3(256 / 64, 32768 / 64), blk, 0, stream>>>(
        x, xt_w1, xt_b1, b_t1, 32768, 256, 32, 0.01f, 1);
    gemm_f32<<<dim3(256 / 64, 32768 / 64), blk, 0, stream>>>(
        b_t1, xt_w2, xt_b2, b_res, 32768, 256, 256, 0.f, 0);
    // b_res viewed as [16384, 512] = cx = residual

    // ---- 5 GATv2 layers ----
    for (int L = 0; L < 5; L++) {
        const float* wl  = (const float*)d_in[7 + 4 * L];
        const float* wr  = (const float*)d_in[8 + 4 * L];
        const float* att = (const float*)d_in[9 + 4 * L];
        const float* gb  = (const float*)d_in[10 + 4 * L];
        int Fin = (L == 0) ? 512 : 1024;
        int H   = (L == 4) ? 1 : 2;
        int HC  = H * DD;
        const float* hin = (L == 0) ? b_res : b_h;

        gemm_f32<<<dim3(HC / 64, NN / 64), blk, 0, stream>>>(
            hin, wl, (const float*)nullptr, b_xl, NN, HC, Fin, 0.f, 0);
        gemm_f32<<<dim3(HC / 64, NN / 64), blk, 0, stream>>>(
            hin, wr, (const float*)nullptr, b_xr, NN, HC, Fin, 0.f, 0);
        edge_logits<<<ET / 4, blk, 0, stream>>>(b_xl, b_xr, att, ei, f_logit, H, HC);
        gat_aggregate<<<NN, blk, 0, stream>>>(
            b_xl, f_logit, gb, i_rs, i_src, i_eid,
            (L == 4) ? b_res : (const float*)nullptr, b_h, H, HC);
    }

    // ---- graph LayerNorm + softmax aggregation ----
    ln_stats<<<BBG, blk, 0, stream>>>(b_h, f_lnm, f_lni);
    graph_aggr<<<dim3(BBG, 2), blk, 0, stream>>>(
        b_h, f_lnm, f_lni, ln_w, ln_b, aggr_t, b_g);

    // ---- head MLP 512 -> 384 -> 256 -> 128 ----
    gemm_f32<<<dim3(384 / 64, 1), blk, 0, stream>>>(
        b_g, m_w1, m_b1, b_m1, 64, 384, 512, 0.01f, 1);
    gemm_f32<<<dim3(256 / 64, 1), blk, 0, stream>>>(
        b_m1, m_w2, m_b2, b_m2, 64, 256, 384, 0.01f, 1);
    gemm_f32<<<dim3(128 / 64, 1), blk, 0, stream>>>(
        b_m2, m_w3, m_b3, out, 64, 128, 256, 0.f, 0);
}

// Round 3
// 1638.769 us; speedup vs baseline: 3.8405x; 3.8405x over previous
//
#include <hip/hip_runtime.h>
#include <hip/hip_bf16.h>

typedef __hip_bfloat16 bf16;

#define NN 16384          // gate nodes
#define BBG 64            // graphs
#define EE 49152          // directed edges (no self loops)
#define ET (EE + NN)      // edges + self loops = 65536
#define DD 512            // node feature dim (2F)
#define NG (NN / BBG)     // 256 nodes per graph
#define MAXDEG 96

__device__ __forceinline__ float b2f(bf16 v) { return __bfloat162float(v); }
__device__ __forceinline__ bf16 f2b(float v) { return __float2bfloat16(v); }
__device__ __forceinline__ int clampi(int v, int lo, int hi)
{
    return v < lo ? lo : (v > hi ? hi : v);
}

typedef __attribute__((ext_vector_type(8))) short bf16x8;  // 8 bf16 = 4 VGPRs
typedef __attribute__((ext_vector_type(4))) float f32x4;

#define AS1 __attribute__((address_space(1)))
#define AS3 __attribute__((address_space(3)))

// ---------------------------------------------------------------------------
// MFMA bf16 GEMM (m97 structure): C[M,N] = act(A[M,K] @ Bt[N,K]^T + bias).
// 128x128 tile, BK=32, 256 threads (4 waves, 2x2), 4x4 16x16x32 frags/wave.
// global_load_lds width-16 staging (wave-uniform LDS base + lane*16).
// M%128==0, N%128==0, K%32==0. C (fp32) and/or Cb (bf16) outputs, nullable.
// ---------------------------------------------------------------------------
__global__ __launch_bounds__(256) void gemm_mfma_bt(
    const bf16* __restrict__ A, const bf16* __restrict__ Bt,
    const float* __restrict__ bias, float* __restrict__ C,
    bf16* __restrict__ Cb, int M, int N, int K, float slope, int has_act)
{
    __shared__ bf16 As[128 * 32];
    __shared__ bf16 Bs[128 * 32];
    const int tid = threadIdx.x;
    const int w = tid >> 6;          // wave 0..3
    const int l = tid & 63;          // lane
    const int bm = blockIdx.y * 128;
    const int bn = blockIdx.x * 128;
    const int wrow = (w >> 1) * 64;  // wave's 64x64 quadrant
    const int wcol = (w & 1) * 64;
    const int quad = l >> 4;         // 0..3
    const int c16 = l & 15;          // 0..15

    // staging: lane l of wave w covers tile row (w*16 + l/4), k-chunk (l%4)*8
    const int lrow = l >> 2;
    const int lchunk = l & 3;
    const bf16* Ag = A + (size_t)(bm + w * 16 + lrow) * K + lchunk * 8;
    const bf16* Bg = Bt + (size_t)(bn + w * 16 + lrow) * K + lchunk * 8;
    char* AsB = (char*)As;
    char* BsB = (char*)Bs;

    f32x4 acc[4][4] = {};

    for (int k0 = 0; k0 < K; k0 += 32) {
        // tile rows [0,64): LDS bytes [0,4096); rows [64,128): [4096,8192)
        __builtin_amdgcn_global_load_lds((const AS1 void*)(Ag + k0),
            (AS3 void*)(AsB + w * 1024), 16, 0, 0);
        __builtin_amdgcn_global_load_lds((const AS1 void*)(Ag + (size_t)64 * K + k0),
            (AS3 void*)(AsB + 4096 + w * 1024), 16, 0, 0);
        __builtin_amdgcn_global_load_lds((const AS1 void*)(Bg + k0),
            (AS3 void*)(BsB + w * 1024), 16, 0, 0);
        __builtin_amdgcn_global_load_lds((const AS1 void*)(Bg + (size_t)64 * K + k0),
            (AS3 void*)(BsB + 4096 + w * 1024), 16, 0, 0);
        __syncthreads();   // compiler emits vmcnt(0) drain before s_barrier

        bf16x8 a[4], b[4];
#pragma unroll
        for (int i = 0; i < 4; i++) {
            int ra = wrow + i * 16 + c16;           // A row in tile
            a[i] = *(const bf16x8*)(AsB + ra * 64 + quad * 16);
            int rb = wcol + i * 16 + c16;           // Bt row (= C col) in tile
            b[i] = *(const bf16x8*)(BsB + rb * 64 + quad * 16);
        }
#pragma unroll
        for (int i = 0; i < 4; i++)
#pragma unroll
            for (int j = 0; j < 4; j++)
                acc[i][j] = __builtin_amdgcn_mfma_f32_16x16x32_bf16(
                    a[i], b[j], acc[i][j], 0, 0, 0);
        __syncthreads();
    }

    // epilogue: C/D layout col=lane&15, row=quad*4+reg
#pragma unroll
    for (int i = 0; i < 4; i++) {
#pragma unroll
        for (int j = 0; j < 4; j++) {
            int col = bn + wcol + j * 16 + c16;
            float bv = bias ? bias[col] : 0.f;
#pragma unroll
            for (int r = 0; r < 4; r++) {
                int row = bm + wrow + i * 16 + quad * 4 + r;
                float v = acc[i][j][r] + bv;
                if (has_act) v = (v >= 0.f) ? v : v * slope;
                if (C)  C[(size_t)row * N + col] = v;
                if (Cb) Cb[(size_t)row * N + col] = f2b(v);
            }
        }
    }
}

// ---------------------------------------------------------------------------
// fp32 GEMM (head MLP only): C[M,N] = act(A@W + bias). M%64==0,N%64==0,K%16==0
// ---------------------------------------------------------------------------
__global__ __launch_bounds__(256) void gemm_f32(
    const float* __restrict__ A, const float* __restrict__ W,
    const float* __restrict__ bias, float* __restrict__ C,
    int M, int N, int K, float slope, int has_act)
{
    const int BK = 16;
    __shared__ float Asm[BK][64 + 1];
    __shared__ float Wsm[BK][64 + 1];
    int tid = threadIdx.x;
    int bm = blockIdx.y * 64;
    int bn = blockIdx.x * 64;
    int tr = tid >> 4;
    int tc = tid & 15;
    float acc[4][4] = {};

    for (int k0 = 0; k0 < K; k0 += BK) {
        {
            int col = tid & 15;
            int row = tid >> 4;
#pragma unroll
            for (int p = 0; p < 4; p++) {
                int r = row + p * 16;
                Asm[col][r] = A[(size_t)(bm + r) * K + k0 + col];
            }
        }
        {
            int wc = tid & 63;
            int wr = tid >> 6;
#pragma unroll
            for (int p = 0; p < 4; p++) {
                int r = wr + p * 4;
                Wsm[r][wc] = W[(size_t)(k0 + r) * N + bn + wc];
            }
        }
        __syncthreads();
#pragma unroll
        for (int kk = 0; kk < BK; kk++) {
            float a[4], w[4];
#pragma unroll
            for (int i = 0; i < 4; i++) a[i] = Asm[kk][tr * 4 + i];
#pragma unroll
            for (int j = 0; j < 4; j++) w[j] = Wsm[kk][tc * 4 + j];
#pragma unroll
            for (int i = 0; i < 4; i++)
#pragma unroll
                for (int j = 0; j < 4; j++)
                    acc[i][j] += a[i] * w[j];
        }
        __syncthreads();
    }
#pragma unroll
    for (int i = 0; i < 4; i++) {
        int r = bm + tr * 4 + i;
#pragma unroll
        for (int j = 0; j < 4; j++) {
            int cn = bn + tc * 4 + j;
            float v = acc[i][j];
            if (bias) v += bias[cn];
            if (has_act) v = (v >= 0.f) ? v : v * slope;
            C[(size_t)r * N + cn] = v;
        }
    }
}

// ---------------------------------------------------------------------------
// fp32 [R,C] -> bf16 [C,R] tiled transpose-convert. R%32==0, C%32==0.
// ---------------------------------------------------------------------------
__global__ __launch_bounds__(256) void transpose_f2b(
    const float* __restrict__ in, bf16* __restrict__ out, int R, int C)
{
    __shared__ float tile[32][33];
    int c0 = blockIdx.x * 32;
    int r0 = blockIdx.y * 32;
    int tx = threadIdx.x & 31;
    int ty = threadIdx.x >> 5;    // 0..7
#pragma unroll
    for (int k = 0; k < 4; k++) {
        int r = ty + k * 8;
        tile[r][tx] = in[(size_t)(r0 + r) * C + c0 + tx];
    }
    __syncthreads();
#pragma unroll
    for (int k = 0; k < 4; k++) {
        int rr = ty + k * 8;      // output row = input col
        out[(size_t)(c0 + rr) * R + r0 + tx] = f2b(tile[tx][rr]);
    }
}

__global__ void f2b_vec(const float* __restrict__ in, bf16* __restrict__ out, int n)
{
    int i = blockIdx.x * 256 + threadIdx.x;
    if (i < n) out[i] = f2b(in[i]);
}

// ---------------------------------------------------------------------------
// CSR build over dst (self loops: edge ids [EE, ET) are node e-EE)
// ---------------------------------------------------------------------------
__global__ void count_deg(const int* __restrict__ ei, int* __restrict__ deg)
{
    int e = blockIdx.x * 256 + threadIdx.x;
    if (e >= ET) return;
    int d = (e < EE) ? ei[EE + e] : (e - EE);
    d = clampi(d, 0, NN - 1);
    atomicAdd(&deg[d], 1);
}

__global__ __launch_bounds__(256) void scan_deg(const int* __restrict__ deg,
                                                int* __restrict__ rs)
{
    __shared__ int part[256];
    __shared__ int psum[257];
    int tid = threadIdx.x;
    const int per = NN / 256;
    int base = tid * per;
    int s = 0;
    for (int i = 0; i < per; i++) s += deg[base + i];
    part[tid] = s;
    __syncthreads();
    if (tid == 0) {
        int acc = 0;
        for (int i = 0; i < 256; i++) { psum[i] = acc; acc += part[i]; }
        psum[256] = acc;
    }
    __syncthreads();
    int acc = psum[tid];
    for (int i = 0; i < per; i++) { rs[base + i] = acc; acc += deg[base + i]; }
    if (tid == 0) rs[NN] = psum[256];
}

__global__ void fill_csr(const int* __restrict__ ei, const int* __restrict__ rs,
                         int* __restrict__ cur, int* __restrict__ csrc,
                         int* __restrict__ ceid)
{
    int e = blockIdx.x * 256 + threadIdx.x;
    if (e >= ET) return;
    int s, d;
    if (e < EE) { s = ei[e]; d = ei[EE + e]; } else { s = d = e - EE; }
    s = clampi(s, 0, NN - 1);
    d = clampi(d, 0, NN - 1);
    int pos = atomicAdd(&cur[d], 1);
    int slot = clampi(rs[d] + pos, 0, ET - 1);
    csrc[slot] = s;
    ceid[slot] = e;
}

// ---------------------------------------------------------------------------
// Edge logits: one wave per edge (bf16 xl/xr)
// ---------------------------------------------------------------------------
__global__ __launch_bounds__(256) void edge_logits(
    const bf16* __restrict__ xl, const bf16* __restrict__ xr,
    const float* __restrict__ att, const int* __restrict__ ei,
    float* __restrict__ logit, int H, int HC)
{
    int e = blockIdx.x * 4 + (threadIdx.x >> 6);
    if (e >= ET) return;
    int lane = threadIdx.x & 63;
    int s, d;
    if (e < EE) { s = ei[e]; d = ei[EE + e]; } else { s = d = e - EE; }
    s = clampi(s, 0, NN - 1);
    d = clampi(d, 0, NN - 1);
    for (int h = 0; h < H; h++) {
        const bf16* pl = xl + (size_t)s * HC + h * DD;
        const bf16* pr = xr + (size_t)d * HC + h * DD;
        const float* pa = att + h * DD;
        float acc = 0.f;
        for (int c = lane; c < DD; c += 64) {
            float v = b2f(pl[c]) + b2f(pr[c]);
            v = (v >= 0.f) ? v : 0.2f * v;
            acc += pa[c] * v;
        }
#pragma unroll
        for (int off = 32; off; off >>= 1) acc += __shfl_down(acc, off);
        if (lane == 0) logit[(size_t)e * H + h] = acc;
    }
}

// ---------------------------------------------------------------------------
// Per-node softmax over in-edges + aggregation of xl[src] (bf16 gather).
// Writes fp32 out_f and/or bf16 out_b (nullable).
// ---------------------------------------------------------------------------
__global__ __launch_bounds__(256) void gat_aggregate(
    const bf16* __restrict__ xl, const float* __restrict__ logit,
    const float* __restrict__ bias, const int* __restrict__ rs,
    const int* __restrict__ csrc, const int* __restrict__ ceid,
    const float* __restrict__ res, float* __restrict__ out_f,
    bf16* __restrict__ out_b, int H, int HC)
{
    int n = blockIdx.x;
    int tid = threadIdx.x;
    int start = rs[n];
    int deg = rs[n + 1] - start;
    deg = clampi(deg, 1, MAXDEG);
    start = clampi(start, 0, ET - 1);
    __shared__ float s_alpha[2 * MAXDEG];
    __shared__ int s_src[MAXDEG];
    if (tid == 0) {
        for (int h = 0; h < H; h++) {
            float m = -1e30f;
            for (int i = 0; i < deg; i++) {
                int eid = clampi(ceid[start + i], 0, ET - 1);
                m = fmaxf(m, logit[(size_t)eid * H + h]);
            }
            float den = 0.f;
            for (int i = 0; i < deg; i++) {
                int eid = clampi(ceid[start + i], 0, ET - 1);
                float p = __expf(logit[(size_t)eid * H + h] - m);
                s_alpha[h * MAXDEG + i] = p;
                den += p;
            }
            float inv = 1.f / den;
            for (int i = 0; i < deg; i++) s_alpha[h * MAXDEG + i] *= inv;
        }
    }
    if (tid < deg) s_src[tid] = clampi(csrc[start + tid], 0, NN - 1);
    __syncthreads();
    for (int c = tid; c < HC; c += 256) {
        int h = c / DD;
        float acc = bias[c];
        for (int i = 0; i < deg; i++)
            acc += s_alpha[h * MAXDEG + i] * b2f(xl[(size_t)s_src[i] * HC + c]);
        acc = (acc >= 0.f) ? acc : 0.01f * acc;
        if (res) acc += res[(size_t)n * HC + c];
        if (out_f) out_f[(size_t)n * HC + c] = acc;
        if (out_b) out_b[(size_t)n * HC + c] = f2b(acc);
    }
}

// ---------------------------------------------------------------------------
// Graph LayerNorm stats over (256 nodes x 512 ch) per graph (fp32 h)
// ---------------------------------------------------------------------------
__global__ __launch_bounds__(256) void ln_stats(const float* __restrict__ h,
                                                float* __restrict__ mean,
                                                float* __restrict__ inv)
{
    int g = blockIdx.x;
    int tid = threadIdx.x;
    const int tot = NG * DD;
    size_t base = (size_t)g * tot;
    float s = 0.f, s2 = 0.f;
    for (int i = tid; i < tot; i += 256) {
        float v = h[base + i];
        s += v; s2 += v * v;
    }
    __shared__ float ls[256], ls2[256];
    ls[tid] = s; ls2[tid] = s2;
    __syncthreads();
    for (int o = 128; o; o >>= 1) {
        if (tid < o) { ls[tid] += ls[tid + o]; ls2[tid] += ls2[tid + o]; }
        __syncthreads();
    }
    if (tid == 0) {
        float m = ls[0] / tot;
        float var = ls2[0] / tot - m * m;
        mean[g] = m;
        inv[g] = rsqrtf(fmaxf(var, 0.f) + 1e-5f);
    }
}

// ---------------------------------------------------------------------------
// LN apply + channel-wise softmax aggregation over nodes
// ---------------------------------------------------------------------------
__global__ __launch_bounds__(256) void graph_aggr(
    const float* __restrict__ h, const float* __restrict__ mean,
    const float* __restrict__ inv, const float* __restrict__ lnw,
    const float* __restrict__ lnb, const float* __restrict__ t_,
    float* __restrict__ gout)
{
    int g = blockIdx.x;
    int c = blockIdx.y * 256 + threadIdx.x;
    float mu = mean[g], iv = inv[g];
    float w = lnw[c], bia = lnb[c];
    float t = t_[0];
    size_t base = (size_t)g * NG * DD + c;
    float mx = -1e30f;
    for (int i = 0; i < NG; i++) {
        float hn = (h[base + (size_t)i * DD] - mu) * iv * w + bia;
        mx = fmaxf(mx, hn * t);
    }
    float den = 0.f, acc = 0.f;
    for (int i = 0; i < NG; i++) {
        float hn = (h[base + (size_t)i * DD] - mu) * iv * w + bia;
        float p = __expf(hn * t - mx);
        den += p;
        acc += p * hn;
    }
    gout[(size_t)g * DD + c] = acc / den;
}

// ---------------------------------------------------------------------------
extern "C" void kernel_launch(void* const* d_in, const int* in_sizes, int n_in,
                              void* d_out, int out_size, void* d_ws, size_t ws_size,
                              hipStream_t stream)
{
    const float* x      = (const float*)d_in[0];
    const int*   ei     = (const int*)d_in[1];
    const float* xt_w1  = (const float*)d_in[3];
    const float* xt_b1  = (const float*)d_in[4];
    const float* xt_w2  = (const float*)d_in[5];
    const float* xt_b2  = (const float*)d_in[6];
    const float* ln_w   = (const float*)d_in[27];
    const float* ln_b   = (const float*)d_in[28];
    const float* aggr_t = (const float*)d_in[29];
    const float* m_w1   = (const float*)d_in[30];
    const float* m_b1   = (const float*)d_in[31];
    const float* m_w2   = (const float*)d_in[32];
    const float* m_b2   = (const float*)d_in[33];
    const float* m_w3   = (const float*)d_in[34];
    const float* m_b3   = (const float*)d_in[35];
    float* out = (float*)d_out;

    // ---- workspace layout (256B aligned); ints first ----
    char* p = (char*)d_ws;
    auto take = [&](size_t bytes) {
        char* r = p;
        p += (bytes + 255) & ~(size_t)255;
        return r;
    };
    int* i_deg     = (int*)take((size_t)(NN + 1) * 4);
    int* i_rs      = (int*)take((size_t)(NN + 1) * 4);
    int* i_cur     = (int*)take((size_t)NN * 4);
    int* i_src     = (int*)take((size_t)ET * 4);
    int* i_eid     = (int*)take((size_t)ET * 4);
    float* f_logit = (float*)take((size_t)ET * 2 * 4);
    float* f_lnm   = (float*)take(BBG * 4);
    float* f_lni   = (float*)take(BBG * 4);
    float* b_g     = (float*)take((size_t)BBG * DD * 4);
    float* b_m1    = (float*)take((size_t)BBG * 384 * 4);
    float* b_m2    = (float*)take((size_t)BBG * 256 * 4);
    float* b_res   = (float*)take((size_t)NN * DD * 4);     // fp32 residual
    float* b_h     = (float*)take((size_t)NN * DD * 4);     // fp32 final h (L4)
    bf16* b_resb   = (bf16*)take((size_t)NN * DD * 2);      // bf16 cx (L0 input)
    bf16* b_hb     = (bf16*)take((size_t)NN * 1024 * 2);    // bf16 h (alias t1b)
    bf16* b_xlb    = (bf16*)take((size_t)NN * 1024 * 2);    // bf16 xl
    bf16* b_xrb    = (bf16*)take((size_t)NN * 1024 * 2);    // bf16 xr
    bf16* b_xb     = (bf16*)take((size_t)2 * NN * 32 * 2);  // bf16 x
    bf16* b_wlb    = (bf16*)take((size_t)1024 * 1024 * 2);  // bf16 wl^T
    bf16* b_wrb    = (bf16*)take((size_t)1024 * 1024 * 2);  // bf16 wr^T
    bf16* b_w1b    = (bf16*)take((size_t)32 * 256 * 2);     // xt_w1^T
    bf16* b_w2b    = (bf16*)take((size_t)256 * 256 * 2);    // xt_w2^T
    bf16* b_t1b = b_hb;   // [32768,256] x_trans intermediate, dead before GAT

    dim3 blk(256);

    // ---- CSR build ----
    hipMemsetAsync(i_deg, 0, (size_t)(NN + 1) * 4, stream);
    hipMemsetAsync(i_cur, 0, (size_t)NN * 4, stream);
    count_deg<<<ET / 256, blk, 0, stream>>>(ei, i_deg);
    scan_deg<<<1, blk, 0, stream>>>(i_deg, i_rs);
    fill_csr<<<ET / 256, blk, 0, stream>>>(ei, i_rs, i_cur, i_src, i_eid);

    // ---- weight converts for x_trans + x convert ----
    f2b_vec<<<(2 * NN * 32 + 255) / 256, blk, 0, stream>>>(x, b_xb, 2 * NN * 32);
    transpose_f2b<<<dim3(256 / 32, 32 / 32), blk, 0, stream>>>(xt_w1, b_w1b, 32, 256);
    transpose_f2b<<<dim3(256 / 32, 256 / 32), blk, 0, stream>>>(xt_w2, b_w2b, 256, 256);

    // ---- x_trans: [32768,32] -> lr -> [32768,256] -> [32768,256] ----
    gemm_mfma_bt<<<dim3(256 / 128, 32768 / 128), blk, 0, stream>>>(
        b_xb, b_w1b, xt_b1, (float*)nullptr, b_t1b, 32768, 256, 32, 0.01f, 1);
    gemm_mfma_bt<<<dim3(256 / 128, 32768 / 128), blk, 0, stream>>>(
        b_t1b, b_w2b, xt_b2, b_res, b_resb, 32768, 256, 256, 0.f, 0);
    // b_res/b_resb viewed as [16384, 512] = cx = residual

    // ---- 5 GATv2 layers ----
    for (int L = 0; L < 5; L++) {
        const float* wl  = (const float*)d_in[7 + 4 * L];
        const float* wr  = (const float*)d_in[8 + 4 * L];
        const float* att = (const float*)d_in[9 + 4 * L];
        const float* gb  = (const float*)d_in[10 + 4 * L];
        int Fin = (L == 0) ? 512 : 1024;
        int H   = (L == 4) ? 1 : 2;
        int HC  = H * DD;
        const bf16* hin = (L == 0) ? b_resb : b_hb;

        transpose_f2b<<<dim3(HC / 32, Fin / 32), blk, 0, stream>>>(wl, b_wlb, Fin, HC);
        transpose_f2b<<<dim3(HC / 32, Fin / 32), blk, 0, stream>>>(wr, b_wrb, Fin, HC);
        gemm_mfma_bt<<<dim3(HC / 128, NN / 128), blk, 0, stream>>>(
            hin, b_wlb, (const float*)nullptr, (float*)nullptr, b_xlb,
            NN, HC, Fin, 0.f, 0);
        gemm_mfma_bt<<<dim3(HC / 128, NN / 128), blk, 0, stream>>>(
            hin, b_wrb, (const float*)nullptr, (float*)nullptr, b_xrb,
            NN, HC, Fin, 0.f, 0);
        edge_logits<<<ET / 4, blk, 0, stream>>>(b_xlb, b_xrb, att, ei, f_logit, H, HC);
        gat_aggregate<<<NN, blk, 0, stream>>>(
            b_xlb, f_logit, gb, i_rs, i_src, i_eid,
            (L == 4) ? b_res : (const float*)nullptr,
            (L == 4) ? b_h : (float*)nullptr,
            (L == 4) ? (bf16*)nullptr : b_hb, H, HC);
    }

    // ---- graph LayerNorm + softmax aggregation ----
    ln_stats<<<BBG, blk, 0, stream>>>(b_h, f_lnm, f_lni);
    graph_aggr<<<dim3(BBG, 2), blk, 0, stream>>>(
        b_h, f_lnm, f_lni, ln_w, ln_b, aggr_t, b_g);

    // ---- head MLP 512 -> 384 -> 256 -> 128 (fp32) ----
    gemm_f32<<<dim3(384 / 64, 1), blk, 0, stream>>>(
        b_g, m_w1, m_b1, b_m1, 64, 384, 512, 0.01f, 1);
    gemm_f32<<<dim3(256 / 64, 1), blk, 0, stream>>>(
        b_m1, m_w2, m_b2, b_m2, 64, 256, 384, 0.01f, 1);
    gemm_f32<<<dim3(128 / 64, 1), blk, 0, stream>>>(
        b_m2, m_w3, m_b3, out, 64, 128, 256, 0.f, 0);
}